// Round 13
// baseline (215.718 us; speedup 1.0000x reference)
//
#include <hip/hip_runtime.h>
#include <hip/hip_bf16.h>

#define HID 1024
#define NHEADS 16
#define HDIM 64
#define SEQ 2048
#define NTOK 4096

typedef __attribute__((ext_vector_type(8))) short short8;
typedef __attribute__((ext_vector_type(4))) float f32x4;
typedef unsigned short ush;

__device__ __forceinline__ ush f2bf(float f) {
    unsigned int u = __float_as_uint(f);
    u = (u + 0x7fffu + ((u >> 16) & 1u)) >> 16;
    return (ush)u;
}
__device__ __forceinline__ void async_copy16(const void* g, void* l) {
    __builtin_amdgcn_global_load_lds(
        (const __attribute__((address_space(1))) void*)g,
        (__attribute__((address_space(3))) void*)l, 16, 0, 0);
}
#define SBAR()  __builtin_amdgcn_s_barrier()
#define SCHED() __builtin_amdgcn_sched_barrier(0)

// ---------------- Kernel 0: f32 -> bf16 convert (X and stacked W) ----------------
__global__ __launch_bounds__(256) void cvt_kernel(
    const float* __restrict__ X, const float* __restrict__ Wq,
    const float* __restrict__ Wk, const float* __restrict__ Wg,
    ush* __restrict__ Xbf, ush* __restrict__ Wbf)
{
    long i = (long)blockIdx.x * 256 + threadIdx.x;   // 917504 vec8 groups
    const float* src; ush* dst; long j;
    if (i < 524288)      { src = X;  dst = Xbf;           j = i; }
    else if (i < 655360) { src = Wq; dst = Wbf;           j = i - 524288; }
    else if (i < 786432) { src = Wk; dst = Wbf + 1048576; j = i - 655360; }
    else                 { src = Wg; dst = Wbf + 2097152; j = i - 786432; }
    float4 a = *reinterpret_cast<const float4*>(src + j * 8);
    float4 b = *reinterpret_cast<const float4*>(src + j * 8 + 4);
    short8 o;
    o[0] = (short)f2bf(a.x); o[1] = (short)f2bf(a.y);
    o[2] = (short)f2bf(a.z); o[3] = (short)f2bf(a.w);
    o[4] = (short)f2bf(b.x); o[5] = (short)f2bf(b.y);
    o[6] = (short)f2bf(b.z); o[7] = (short)f2bf(b.w);
    *reinterpret_cast<short8*>(dst + j * 8) = o;
}

// ---------------- Kernel 1: fused projection GEMM (N = 3072 = Q|K|gate) ----------------
__global__ __launch_bounds__(256, 3) void proj_kernel(
    const ush* __restrict__ Xbf, const ush* __restrict__ Wbf,
    const float* __restrict__ bgp,
    ush* __restrict__ Qbf, ush* __restrict__ Kbf,
    ush* __restrict__ VtG,
    float* __restrict__ gate)
{
    __shared__ __align__(16) ush As[128 * 64];
    __shared__ __align__(16) ush Bs[128 * 64];

    const int lin = blockIdx.y * 24 + blockIdx.x;   // 768 blocks, 768%8==0
    const int swz = (lin & 7) * 96 + (lin >> 3);
    const int n0 = (swz % 24) * 128;
    const int m0 = (swz / 24) * 128;
    const int tid = threadIdx.x, lane = tid & 63, wv = tid >> 6;
    const int wm = wv >> 1, wn = wv & 1;
    const int l16 = lane & 15, lq = lane >> 4;
    const int lrow = lane >> 3, lc = lane & 7;
    const int scU = lc ^ lrow;
    const int u0 = lq ^ (l16 & 7);

    f32x4 acc[4][4];
    #pragma unroll
    for (int i = 0; i < 4; i++)
        #pragma unroll
        for (int j = 0; j < 4; j++)
            #pragma unroll
            for (int r = 0; r < 4; r++) acc[i][j][r] = 0.0f;

    const ush* gA = Xbf + (long)m0 * HID;
    const ush* gB = Wbf + (long)n0 * HID;

    for (int k0 = 0; k0 < HID; k0 += 64) {
        #pragma unroll
        for (int c = 0; c < 4; ++c) {
            int chunk = wv * 4 + c;                  // wave-uniform
            int row = chunk * 8 + lrow;
            async_copy16(gA + (long)row * HID + k0 + scU * 8, &As[chunk * 512]);
            async_copy16(gB + (long)row * HID + k0 + scU * 8, &Bs[chunk * 512]);
        }
        asm volatile("s_waitcnt vmcnt(0)" ::: "memory");
        SCHED();
        SBAR(); SCHED();
        #pragma unroll
        for (int ks = 0; ks < 2; ++ks) {
            const int uo = (ks ? (u0 ^ 4) : u0) * 8;
            short8 a[4], b[4];
            #pragma unroll
            for (int mf = 0; mf < 4; mf++)
                a[mf] = *reinterpret_cast<const short8*>(&As[(wm * 64 + mf * 16 + l16) * 64 + uo]);
            #pragma unroll
            for (int nf = 0; nf < 4; nf++)
                b[nf] = *reinterpret_cast<const short8*>(&Bs[(wn * 64 + nf * 16 + l16) * 64 + uo]);
            #pragma unroll
            for (int mf = 0; mf < 4; mf++)
                #pragma unroll
                for (int nf = 0; nf < 4; nf++)
                    acc[mf][nf] = __builtin_amdgcn_mfma_f32_16x16x32_bf16(a[mf], b[nf], acc[mf][nf], 0, 0, 0);
        }
        SBAR(); SCHED();
    }

    const int z = n0 >> 10;   // 0=Q, 1=K, 2=gate
    #pragma unroll
    for (int mf = 0; mf < 4; mf++)
        #pragma unroll
        for (int nf = 0; nf < 4; nf++) {
            int row = m0 + wm * 64 + mf * 16 + lq * 4;
            int gcol = n0 + wn * 64 + nf * 16 + l16;
            int col = gcol & 1023;
            #pragma unroll
            for (int r = 0; r < 4; r++) {
                float v = acc[mf][nf][r];
                long idx = (long)(row + r) * HID + col;
                if (z == 0)      Qbf[idx] = f2bf(v * 0.18033688011112042f); // 0.125*log2e
                else if (z == 1) Kbf[idx] = f2bf(v);
                else {
                    float gv = 1.0f / (1.0f + __expf(-(v + bgp[col])));
                    __builtin_nontemporal_store(gv, &gate[idx]);
                }
            }
            if (z == 1) {
                int bb = row >> 11, s = row & 2047;
                int bh = bb * NHEADS + (col >> 6);
                int d  = col & 63;
                unsigned int w0, w1;
                asm volatile("v_cvt_pk_bf16_f32 %0, %1, %2" : "=v"(w0)
                             : "v"(acc[mf][nf][0]), "v"(acc[mf][nf][1]));
                asm volatile("v_cvt_pk_bf16_f32 %0, %1, %2" : "=v"(w1)
                             : "v"(acc[mf][nf][2]), "v"(acc[mf][nf][3]));
                *reinterpret_cast<uint2*>(&VtG[((long)bh * HDIM + d) * SEQ + s]) =
                    make_uint2(w0, w1);
            }
        }
}

// ---------------- Kernel 2: attention, 3-sweep + 4-iter batched stores ----------------
// Writing sweeps defer attn stores in registers for 4 iterations, then flush
// 1KB-contiguous-per-row clusters (DRAM write locality 4x).
__global__ __launch_bounds__(256, 2) void attn_kernel(
    const ush* __restrict__ Qbf,
    const ush* __restrict__ Kbf,
    const ush* __restrict__ VtG,
    float* __restrict__ outp,      // [4096][1024], holds gate on entry
    float* __restrict__ attnp)     // [32][2048][2048]
{
    __shared__ __align__(16) ush QsA[3 * 4096];   // 24 KB  Q 3-slot rotation
    __shared__ __align__(16) ush AtA[64 * 72];    // 9.2 KB K staging scratch / P tile
    __shared__ __align__(16) ush VtA[3 * 4096];   // 24 KB  V 3-slot rotation

    ush (*At)[72] = reinterpret_cast<ush(*)[72]>(&AtA[0]);

    const int lin  = blockIdx.x;                    // 512 blocks, %8==0
    const int swzb = (lin & 7) * 64 + (lin >> 3);
    const int rh   = swzb & 1;
    const int pair = (swzb >> 1) & 7;
    const int h    = (swzb >> 4) & 15;
    const int b    = swzb >> 8;
    const int bh   = b * NHEADS + h;
    const int tb   = b * SEQ;
    const int colbase = h * HDIM;
    const int rowbase_a = pair * 256 + rh * 64;     // kb_a*128 + rh*64
    const int rowbase_b = rowbase_a + 128;          // kb_b*128 + rh*64

    const int tid  = threadIdx.x;
    const int lane = tid & 63;
    const int wv   = tid >> 6;
    const int l16  = lane & 15, lq = lane >> 4;
    const int u0   = lq ^ (l16 & 7);
    const int rlo  = lane >> 4;            // 0..3
    const int qc2  = (lane & 15) * 4;      // 0..60

    auto stageT = [&](const ush* src, long stride, ush* dst) {
        #pragma unroll
        for (int c = 0; c < 2; ++c) {
            int p = c * 256 + tid;
            int row = p >> 3, lc2 = p & 7;
            int scU2 = lc2 ^ (row & 7);
            async_copy16(src + (long)row * stride + scU2 * 8, dst + c * 2048 + wv * 512);
        }
    };
    const ush* Qsrc = Qbf + (long)tb * HID + colbase;
    const ush* Vsrc = VtG + (long)bh * HDIM * SEQ;

    // ---- K(a), K(b) -> registers via AtA staging ----
    short8 bk_a[2], bk_b[2];
    {
        stageT(Kbf + (long)(tb + rowbase_a) * HID + colbase, HID, AtA);
        asm volatile("s_waitcnt vmcnt(0)" ::: "memory"); SCHED();
        SBAR(); SCHED();
        #pragma unroll
        for (int ks = 0; ks < 2; ++ks) {
            const int uo = (ks ? (u0 ^ 4) : u0) * 8;
            bk_a[ks] = *reinterpret_cast<const short8*>(&AtA[(wv * 16 + l16) * 64 + uo]);
        }
        SBAR(); SCHED();
        stageT(Kbf + (long)(tb + rowbase_b) * HID + colbase, HID, AtA);
        asm volatile("s_waitcnt vmcnt(0)" ::: "memory"); SCHED();
        SBAR(); SCHED();
        #pragma unroll
        for (int ks = 0; ks < 2; ++ks) {
            const int uo = (ks ? (u0 ^ 4) : u0) * 8;
            bk_b[ks] = *reinterpret_cast<const short8*>(&AtA[(wv * 16 + l16) * 64 + uo]);
        }
        SBAR(); SCHED();
    }

    // ======== sweep 1: denom(a) ========
    stageT(Qsrc, HID, &QsA[0]);
    stageT(Qsrc + (long)64 * HID, HID, &QsA[4096]);

    float ps_a = 0.0f;
    for (int i = 0; i < 32; ++i) {
        if (i >= 30) asm volatile("s_waitcnt vmcnt(0)" ::: "memory");
        else         asm volatile("s_waitcnt vmcnt(2)" ::: "memory");
        SCHED();
        SBAR(); SCHED();
        if (i < 30) stageT(Qsrc + (long)((i + 2) * 64) * HID, HID, &QsA[((i + 2) % 3) * 4096]);

        f32x4 acc[4];
        #pragma unroll
        for (int x = 0; x < 4; x++)
            #pragma unroll
            for (int r = 0; r < 4; r++) acc[x][r] = 0.0f;

        const ush* Qb = &QsA[(i % 3) * 4096];
        __builtin_amdgcn_s_setprio(1);
        #pragma unroll
        for (int ks = 0; ks < 2; ks++) {
            const int uo = (ks ? (u0 ^ 4) : u0) * 8;
            short8 aq[4];
            #pragma unroll
            for (int mf = 0; mf < 4; mf++)
                aq[mf] = *reinterpret_cast<const short8*>(&Qb[(mf * 16 + l16) * 64 + uo]);
            #pragma unroll
            for (int mf = 0; mf < 4; mf++)
                acc[mf] = __builtin_amdgcn_mfma_f32_16x16x32_bf16(aq[mf], bk_a[ks], acc[mf], 0, 0, 0);
        }
        __builtin_amdgcn_s_setprio(0);

        #pragma unroll
        for (int mf = 0; mf < 4; mf++) {
            float s = 0.0f;
            #pragma unroll
            for (int r = 0; r < 4; r++) s += exp2f(acc[mf][r]);
            ps_a += s;
        }
    }
    float inv_a;
    {
        float v = ps_a;
        v += __shfl_xor(v, 16);
        v += __shfl_xor(v, 32);
        inv_a = 1.0f / v;
    }

    // ======== sweep 2: B(a) + denom(b), batched stores ========
    SBAR();
    stageT(Qsrc, HID, &QsA[0]);
    stageT(Vsrc, SEQ, &VtA[0]);
    stageT(Qsrc + (long)64 * HID, HID, &QsA[4096]);
    stageT(Vsrc + 64, SEQ, &VtA[4096]);

    float ps_b = 0.0f;
    f32x4 octx[4];
    #pragma unroll
    for (int y = 0; y < 4; y++)
        #pragma unroll
        for (int r = 0; r < 4; r++) octx[y][r] = 0.0f;

    for (int g4 = 0; g4 < 8; ++g4) {
        uint2 dreg[4][4];   // [gi][j] — all compile-time indexed
        #pragma unroll
        for (int gi = 0; gi < 4; ++gi) {
            const int i = g4 * 4 + gi;
            if (g4 == 0 && gi < 2) { asm volatile("s_waitcnt vmcnt(4)"  ::: "memory"); }
            else if (gi < 2)       { asm volatile("s_waitcnt vmcnt(20)" ::: "memory"); }
            else                   { asm volatile("s_waitcnt vmcnt(4)"  ::: "memory"); }
            SCHED();
            SBAR(); SCHED();
            if (i < 30) {
                stageT(Qsrc + (long)((i + 2) * 64) * HID, HID, &QsA[((i + 2) % 3) * 4096]);
                stageT(Vsrc + (i + 2) * 64, SEQ, &VtA[((i + 2) % 3) * 4096]);
            }

            f32x4 aA[4], aB[4];
            #pragma unroll
            for (int x = 0; x < 4; x++)
                #pragma unroll
                for (int r = 0; r < 4; r++) { aA[x][r] = 0.0f; aB[x][r] = 0.0f; }

            const ush* Qb = &QsA[(i % 3) * 4096];
            __builtin_amdgcn_s_setprio(1);
            #pragma unroll
            for (int ks = 0; ks < 2; ks++) {
                const int uo = (ks ? (u0 ^ 4) : u0) * 8;
                short8 aq[4];
                #pragma unroll
                for (int mf = 0; mf < 4; mf++)
                    aq[mf] = *reinterpret_cast<const short8*>(&Qb[(mf * 16 + l16) * 64 + uo]);
                #pragma unroll
                for (int mf = 0; mf < 4; mf++)
                    aA[mf] = __builtin_amdgcn_mfma_f32_16x16x32_bf16(aq[mf], bk_a[ks], aA[mf], 0, 0, 0);
                #pragma unroll
                for (int mf = 0; mf < 4; mf++)
                    aB[mf] = __builtin_amdgcn_mfma_f32_16x16x32_bf16(aq[mf], bk_b[ks], aB[mf], 0, 0, 0);
            }
            __builtin_amdgcn_s_setprio(0);

            // softmax(a) -> At (wave-private 16 rows)
            {
                const int krl = wv * 16 + l16;
                #pragma unroll
                for (int mf = 0; mf < 4; mf++) {
                    const int qc = mf * 16 + lq * 4;
                    float p0 = exp2f(aA[mf][0]) * inv_a;
                    float p1 = exp2f(aA[mf][1]) * inv_a;
                    float p2 = exp2f(aA[mf][2]) * inv_a;
                    float p3 = exp2f(aA[mf][3]) * inv_a;
                    unsigned int w0, w1;
                    asm volatile("v_cvt_pk_bf16_f32 %0, %1, %2" : "=v"(w0) : "v"(p0), "v"(p1));
                    asm volatile("v_cvt_pk_bf16_f32 %0, %1, %2" : "=v"(w1) : "v"(p2), "v"(p3));
                    *reinterpret_cast<uint2*>(&At[krl][qc]) = make_uint2(w0, w1);
                }
            }
            asm volatile("s_waitcnt lgkmcnt(0)" ::: "memory");
            SCHED();

            #pragma unroll
            for (int j = 0; j < 4; ++j)
                dreg[gi][j] = *reinterpret_cast<const uint2*>(&At[wv * 16 + j * 4 + rlo][qc2]);

            // PV(a) from V slot i%3
            const ush* Vb = &VtA[(i % 3) * 4096];
            __builtin_amdgcn_s_setprio(1);
            #pragma unroll
            for (int ks = 0; ks < 2; ks++) {
                const int uo = (ks ? (u0 ^ 4) : u0) * 8;
                short8 a = *reinterpret_cast<const short8*>(&At[wv * 16 + l16][ks * 32 + lq * 8]);
                #pragma unroll
                for (int nf = 0; nf < 4; nf++) {
                    short8 bv = *reinterpret_cast<const short8*>(&Vb[(nf * 16 + l16) * 64 + uo]);
                    octx[nf] = __builtin_amdgcn_mfma_f32_16x16x32_bf16(a, bv, octx[nf], 0, 0, 0);
                }
            }
            __builtin_amdgcn_s_setprio(0);

            // denom(b)
            #pragma unroll
            for (int mf = 0; mf < 4; mf++) {
                float s = 0.0f;
                #pragma unroll
                for (int r = 0; r < 4; r++) s += exp2f(aB[mf][r]);
                ps_b += s;
            }
        }

        // flush: per row j, 4x 16B covering a contiguous 1KB window
        #pragma unroll
        for (int j = 0; j < 4; ++j) {
            const int rl = rowbase_a + wv * 16 + j * 4 + rlo;
            const long rb = ((long)bh * SEQ + rl) * SEQ;
            #pragma unroll
            for (int gi = 0; gi < 4; ++gi) {
                f32x4 st;
                st[0] = __uint_as_float(dreg[gi][j].x << 16);
                st[1] = __uint_as_float(dreg[gi][j].x & 0xffff0000u);
                st[2] = __uint_as_float(dreg[gi][j].y << 16);
                st[3] = __uint_as_float(dreg[gi][j].y & 0xffff0000u);
                __builtin_nontemporal_store(st,
                    reinterpret_cast<f32x4*>(attnp + rb + (g4 * 4 + gi) * 64 + qc2));
            }
        }
    }
    float inv_b;
    {
        float v = ps_b;
        v += __shfl_xor(v, 16);
        v += __shfl_xor(v, 32);
        inv_b = 1.0f / v;
    }

    // epilogue(a): out = gate * ctx
    #pragma unroll
    for (int nf = 0; nf < 4; nf++) {
        int col = colbase + nf * 16 + l16;
        #pragma unroll
        for (int r = 0; r < 4; r++) {
            long idx = (long)(tb + rowbase_a + wv * 16 + lq * 4 + r) * HID + col;
            float g = __builtin_nontemporal_load(&outp[idx]);
            __builtin_nontemporal_store(g * octx[nf][r], &outp[idx]);
        }
    }

    // ======== sweep 3: B(b), batched stores ========
    SBAR();
    stageT(Qsrc, HID, &QsA[0]);
    stageT(Vsrc, SEQ, &VtA[0]);
    stageT(Qsrc + (long)64 * HID, HID, &QsA[4096]);
    stageT(Vsrc + 64, SEQ, &VtA[4096]);

    #pragma unroll
    for (int y = 0; y < 4; y++)
        #pragma unroll
        for (int r = 0; r < 4; r++) octx[y][r] = 0.0f;

    for (int g4 = 0; g4 < 8; ++g4) {
        uint2 dreg[4][4];
        #pragma unroll
        for (int gi = 0; gi < 4; ++gi) {
            const int i = g4 * 4 + gi;
            if (g4 == 0 && gi < 2) { asm volatile("s_waitcnt vmcnt(4)"  ::: "memory"); }
            else if (gi < 2)       { asm volatile("s_waitcnt vmcnt(20)" ::: "memory"); }
            else                   { asm volatile("s_waitcnt vmcnt(4)"  ::: "memory"); }
            SCHED();
            SBAR(); SCHED();
            if (i < 30) {
                stageT(Qsrc + (long)((i + 2) * 64) * HID, HID, &QsA[((i + 2) % 3) * 4096]);
                stageT(Vsrc + (i + 2) * 64, SEQ, &VtA[((i + 2) % 3) * 4096]);
            }

            f32x4 aB[4];
            #pragma unroll
            for (int x = 0; x < 4; x++)
                #pragma unroll
                for (int r = 0; r < 4; r++) aB[x][r] = 0.0f;

            const ush* Qb = &QsA[(i % 3) * 4096];
            __builtin_amdgcn_s_setprio(1);
            #pragma unroll
            for (int ks = 0; ks < 2; ks++) {
                const int uo = (ks ? (u0 ^ 4) : u0) * 8;
                short8 aq[4];
                #pragma unroll
                for (int mf = 0; mf < 4; mf++)
                    aq[mf] = *reinterpret_cast<const short8*>(&Qb[(mf * 16 + l16) * 64 + uo]);
                #pragma unroll
                for (int mf = 0; mf < 4; mf++)
                    aB[mf] = __builtin_amdgcn_mfma_f32_16x16x32_bf16(aq[mf], bk_b[ks], aB[mf], 0, 0, 0);
            }
            __builtin_amdgcn_s_setprio(0);

            {
                const int krl = wv * 16 + l16;
                #pragma unroll
                for (int mf = 0; mf < 4; mf++) {
                    const int qc = mf * 16 + lq * 4;
                    float p0 = exp2f(aB[mf][0]) * inv_b;
                    float p1 = exp2f(aB[mf][1]) * inv_b;
                    float p2 = exp2f(aB[mf][2]) * inv_b;
                    float p3 = exp2f(aB[mf][3]) * inv_b;
                    unsigned int w0, w1;
                    asm volatile("v_cvt_pk_bf16_f32 %0, %1, %2" : "=v"(w0) : "v"(p0), "v"(p1));
                    asm volatile("v_cvt_pk_bf16_f32 %0, %1, %2" : "=v"(w1) : "v"(p2), "v"(p3));
                    *reinterpret_cast<uint2*>(&At[krl][qc]) = make_uint2(w0, w1);
                }
            }
            asm volatile("s_waitcnt lgkmcnt(0)" ::: "memory");
            SCHED();

            #pragma unroll
            for (int j = 0; j < 4; ++j)
                dreg[gi][j] = *reinterpret_cast<const uint2*>(&At[wv * 16 + j * 4 + rlo][qc2]);

            const ush* Vb = &VtA[(i % 3) * 4096];
            __builtin_amdgcn_s_setprio(1);
            #pragma unroll
            for (int ks = 0; ks < 2; ks++) {
                const int uo = (ks ? (u0 ^ 4) : u0) * 8;
                short8 a = *reinterpret_cast<const short8*>(&At[wv * 16 + l16][ks * 32 + lq * 8]);
                #pragma unroll
                for (int nf = 0; nf < 4; nf++) {
                    short8 bv = *reinterpret_cast<const short8*>(&Vb[(nf * 16 + l16) * 64 + uo]);
                    octx[nf] = __builtin_amdgcn_mfma_f32_16x16x32_bf16(a, bv, octx[nf], 0, 0, 0);
                }
            }
            __builtin_amdgcn_s_setprio(0);
        }

        #pragma unroll
        for (int j = 0; j < 4; ++j) {
            const int rl = rowbase_b + wv * 16 + j * 4 + rlo;
            const long rb = ((long)bh * SEQ + rl) * SEQ;
            #pragma unroll
            for (int gi = 0; gi < 4; ++gi) {
                f32x4 st;
                st[0] = __uint_as_float(dreg[gi][j].x << 16);
                st[1] = __uint_as_float(dreg[gi][j].x & 0xffff0000u);
                st[2] = __uint_as_float(dreg[gi][j].y << 16);
                st[3] = __uint_as_float(dreg[gi][j].y & 0xffff0000u);
                __builtin_nontemporal_store(st,
                    reinterpret_cast<f32x4*>(attnp + rb + (g4 * 4 + gi) * 64 + qc2));
            }
        }
    }

    // epilogue(b)
    #pragma unroll
    for (int nf = 0; nf < 4; nf++) {
        int col = colbase + nf * 16 + l16;
        #pragma unroll
        for (int r = 0; r < 4; r++) {
            long idx = (long)(tb + rowbase_b + wv * 16 + lq * 4 + r) * HID + col;
            float g = __builtin_nontemporal_load(&outp[idx]);
            __builtin_nontemporal_store(g * octx[nf][r], &outp[idx]);
        }
    }
}

extern "C" void kernel_launch(void* const* d_in, const int* in_sizes, int n_in,
                              void* d_out, int out_size, void* d_ws, size_t ws_size,
                              hipStream_t stream)
{
    const float* X  = (const float*)d_in[0];
    const float* Wq = (const float*)d_in[1];
    const float* Wk = (const float*)d_in[2];
    const float* Wg = (const float*)d_in[3];
    const float* bg = (const float*)d_in[4];

    float* outp  = (float*)d_out;
    float* attnp = outp + (long)NTOK * HID;

    ush* Qbf = (ush*)d_ws;
    ush* Kbf = Qbf + (long)NTOK * HID;
    ush* VtG = Kbf + (long)NTOK * HID;

    ush* Xbf = (ush*)(outp + 134742016L);
    ush* Wbf = Xbf + (long)NTOK * HID;

    cvt_kernel<<<3584, 256, 0, stream>>>(X, Wq, Wk, Wg, Xbf, Wbf);
    proj_kernel<<<dim3(24, 32), 256, 0, stream>>>(Xbf, Wbf, bg, Qbf, Kbf, VtG, outp);
    attn_kernel<<<512, 256, 0, stream>>>(Qbf, Kbf, VtG, outp, attnp);
}

// Round 14
// 206.391 us; speedup vs baseline: 1.0452x; 1.0452x over previous
//
#include <hip/hip_runtime.h>
#include <hip/hip_bf16.h>

#define HID 1024
#define NHEADS 16
#define HDIM 64
#define SEQ 2048
#define NTOK 4096

typedef __attribute__((ext_vector_type(8))) short short8;
typedef __attribute__((ext_vector_type(4))) float f32x4;
typedef unsigned short ush;

__device__ __forceinline__ ush f2bf(float f) {
    unsigned int u = __float_as_uint(f);
    u = (u + 0x7fffu + ((u >> 16) & 1u)) >> 16;
    return (ush)u;
}
__device__ __forceinline__ void async_copy16(const void* g, void* l) {
    __builtin_amdgcn_global_load_lds(
        (const __attribute__((address_space(1))) void*)g,
        (__attribute__((address_space(3))) void*)l, 16, 0, 0);
}
#define SBAR()  __builtin_amdgcn_s_barrier()
#define SCHED() __builtin_amdgcn_sched_barrier(0)

// ---------------- Kernel 0: f32 -> bf16 convert (X and stacked W) ----------------
__global__ __launch_bounds__(256) void cvt_kernel(
    const float* __restrict__ X, const float* __restrict__ Wq,
    const float* __restrict__ Wk, const float* __restrict__ Wg,
    ush* __restrict__ Xbf, ush* __restrict__ Wbf)
{
    long i = (long)blockIdx.x * 256 + threadIdx.x;   // 917504 vec8 groups
    const float* src; ush* dst; long j;
    if (i < 524288)      { src = X;  dst = Xbf;           j = i; }
    else if (i < 655360) { src = Wq; dst = Wbf;           j = i - 524288; }
    else if (i < 786432) { src = Wk; dst = Wbf + 1048576; j = i - 655360; }
    else                 { src = Wg; dst = Wbf + 2097152; j = i - 786432; }
    float4 a = *reinterpret_cast<const float4*>(src + j * 8);
    float4 b = *reinterpret_cast<const float4*>(src + j * 8 + 4);
    short8 o;
    o[0] = (short)f2bf(a.x); o[1] = (short)f2bf(a.y);
    o[2] = (short)f2bf(a.z); o[3] = (short)f2bf(a.w);
    o[4] = (short)f2bf(b.x); o[5] = (short)f2bf(b.y);
    o[6] = (short)f2bf(b.z); o[7] = (short)f2bf(b.w);
    *reinterpret_cast<short8*>(dst + j * 8) = o;
}

// ---------------- Kernel 1: fused projection GEMM (N = 3072 = Q|K|gate) ----------------
__global__ __launch_bounds__(256, 3) void proj_kernel(
    const ush* __restrict__ Xbf, const ush* __restrict__ Wbf,
    const float* __restrict__ bgp,
    ush* __restrict__ Qbf, ush* __restrict__ Kbf,
    ush* __restrict__ VtG,
    float* __restrict__ gate)
{
    __shared__ __align__(16) ush As[128 * 64];
    __shared__ __align__(16) ush Bs[128 * 64];

    const int lin = blockIdx.y * 24 + blockIdx.x;   // 768 blocks, 768%8==0
    const int swz = (lin & 7) * 96 + (lin >> 3);
    const int n0 = (swz % 24) * 128;
    const int m0 = (swz / 24) * 128;
    const int tid = threadIdx.x, lane = tid & 63, wv = tid >> 6;
    const int wm = wv >> 1, wn = wv & 1;
    const int l16 = lane & 15, lq = lane >> 4;
    const int lrow = lane >> 3, lc = lane & 7;
    const int scU = lc ^ lrow;
    const int u0 = lq ^ (l16 & 7);

    f32x4 acc[4][4];
    #pragma unroll
    for (int i = 0; i < 4; i++)
        #pragma unroll
        for (int j = 0; j < 4; j++)
            #pragma unroll
            for (int r = 0; r < 4; r++) acc[i][j][r] = 0.0f;

    const ush* gA = Xbf + (long)m0 * HID;
    const ush* gB = Wbf + (long)n0 * HID;

    for (int k0 = 0; k0 < HID; k0 += 64) {
        #pragma unroll
        for (int c = 0; c < 4; ++c) {
            int chunk = wv * 4 + c;                  // wave-uniform
            int row = chunk * 8 + lrow;
            async_copy16(gA + (long)row * HID + k0 + scU * 8, &As[chunk * 512]);
            async_copy16(gB + (long)row * HID + k0 + scU * 8, &Bs[chunk * 512]);
        }
        asm volatile("s_waitcnt vmcnt(0)" ::: "memory");
        SCHED();
        SBAR(); SCHED();
        #pragma unroll
        for (int ks = 0; ks < 2; ++ks) {
            const int uo = (ks ? (u0 ^ 4) : u0) * 8;
            short8 a[4], b[4];
            #pragma unroll
            for (int mf = 0; mf < 4; mf++)
                a[mf] = *reinterpret_cast<const short8*>(&As[(wm * 64 + mf * 16 + l16) * 64 + uo]);
            #pragma unroll
            for (int nf = 0; nf < 4; nf++)
                b[nf] = *reinterpret_cast<const short8*>(&Bs[(wn * 64 + nf * 16 + l16) * 64 + uo]);
            #pragma unroll
            for (int mf = 0; mf < 4; mf++)
                #pragma unroll
                for (int nf = 0; nf < 4; nf++)
                    acc[mf][nf] = __builtin_amdgcn_mfma_f32_16x16x32_bf16(a[mf], b[nf], acc[mf][nf], 0, 0, 0);
        }
        SBAR(); SCHED();
    }

    const int z = n0 >> 10;   // 0=Q, 1=K, 2=gate
    #pragma unroll
    for (int mf = 0; mf < 4; mf++)
        #pragma unroll
        for (int nf = 0; nf < 4; nf++) {
            int row = m0 + wm * 64 + mf * 16 + lq * 4;
            int gcol = n0 + wn * 64 + nf * 16 + l16;
            int col = gcol & 1023;
            #pragma unroll
            for (int r = 0; r < 4; r++) {
                float v = acc[mf][nf][r];
                long idx = (long)(row + r) * HID + col;
                if (z == 0)      Qbf[idx] = f2bf(v * 0.18033688011112042f); // 0.125*log2e
                else if (z == 1) Kbf[idx] = f2bf(v);
                else {
                    float gv = 1.0f / (1.0f + __expf(-(v + bgp[col])));
                    __builtin_nontemporal_store(gv, &gate[idx]);
                }
            }
            if (z == 1) {
                int bb = row >> 11, s = row & 2047;
                int bh = bb * NHEADS + (col >> 6);
                int d  = col & 63;
                unsigned int w0, w1;
                asm volatile("v_cvt_pk_bf16_f32 %0, %1, %2" : "=v"(w0)
                             : "v"(acc[mf][nf][0]), "v"(acc[mf][nf][1]));
                asm volatile("v_cvt_pk_bf16_f32 %0, %1, %2" : "=v"(w1)
                             : "v"(acc[mf][nf][2]), "v"(acc[mf][nf][3]));
                *reinterpret_cast<uint2*>(&VtG[((long)bh * HDIM + d) * SEQ + s]) =
                    make_uint2(w0, w1);
            }
        }
}

// ---------------- Kernel 2: attention, 3-sweep kblk-pair pipeline ----------------
// sweep1: denom(a). sweep2: write+PV(a) + denom(b). sweep3: write+PV(b).
// Writing sweeps: 3-slot V rotation staged at iter top -> ONE barrier/iter,
// V latency covered by 2 iterations, steady vmcnt(12).
__global__ __launch_bounds__(256, 2) void attn_kernel(
    const ush* __restrict__ Qbf,
    const ush* __restrict__ Kbf,
    const ush* __restrict__ VtG,
    float* __restrict__ outp,      // [4096][1024], holds gate on entry
    float* __restrict__ attnp)     // [32][2048][2048]
{
    __shared__ __align__(16) ush QsA[3 * 4096];   // 24 KB  Q 3-slot rotation
    __shared__ __align__(16) ush AtA[64 * 72];    // 9.2 KB K staging scratch / P tile
    __shared__ __align__(16) ush VtA[3 * 4096];   // 24 KB  V 3-slot rotation

    ush (*At)[72] = reinterpret_cast<ush(*)[72]>(&AtA[0]);

    const int lin  = blockIdx.x;                    // 512 blocks, %8==0
    const int swzb = (lin & 7) * 64 + (lin >> 3);
    const int rh   = swzb & 1;
    const int pair = (swzb >> 1) & 7;
    const int h    = (swzb >> 4) & 15;
    const int b    = swzb >> 8;
    const int bh   = b * NHEADS + h;
    const int tb   = b * SEQ;
    const int colbase = h * HDIM;
    const int rowbase_a = pair * 256 + rh * 64;     // kb_a*128 + rh*64
    const int rowbase_b = rowbase_a + 128;          // kb_b*128 + rh*64

    const int tid  = threadIdx.x;
    const int lane = tid & 63;
    const int wv   = tid >> 6;
    const int l16  = lane & 15, lq = lane >> 4;
    const int u0   = lq ^ (l16 & 7);
    const int rlo  = lane >> 4;            // 0..3
    const int qc2  = (lane & 15) * 4;      // 0..60

    // stage a 64x64 bf16 tile with both-sides XOR swizzle (2 copies/thread)
    auto stageT = [&](const ush* src, long stride, ush* dst) {
        #pragma unroll
        for (int c = 0; c < 2; ++c) {
            int p = c * 256 + tid;
            int row = p >> 3, lc2 = p & 7;
            int scU2 = lc2 ^ (row & 7);
            async_copy16(src + (long)row * stride + scU2 * 8, dst + c * 2048 + wv * 512);
        }
    };
    const ush* Qsrc = Qbf + (long)tb * HID + colbase;
    const ush* Vsrc = VtG + (long)bh * HDIM * SEQ;

    // ---- K(a), K(b) -> registers via AtA staging ----
    short8 bk_a[2], bk_b[2];
    {
        stageT(Kbf + (long)(tb + rowbase_a) * HID + colbase, HID, AtA);
        asm volatile("s_waitcnt vmcnt(0)" ::: "memory"); SCHED();
        SBAR(); SCHED();
        #pragma unroll
        for (int ks = 0; ks < 2; ++ks) {
            const int uo = (ks ? (u0 ^ 4) : u0) * 8;
            bk_a[ks] = *reinterpret_cast<const short8*>(&AtA[(wv * 16 + l16) * 64 + uo]);
        }
        SBAR(); SCHED();
        stageT(Kbf + (long)(tb + rowbase_b) * HID + colbase, HID, AtA);
        asm volatile("s_waitcnt vmcnt(0)" ::: "memory"); SCHED();
        SBAR(); SCHED();
        #pragma unroll
        for (int ks = 0; ks < 2; ++ks) {
            const int uo = (ks ? (u0 ^ 4) : u0) * 8;
            bk_b[ks] = *reinterpret_cast<const short8*>(&AtA[(wv * 16 + l16) * 64 + uo]);
        }
        SBAR(); SCHED();
    }

    // ======== sweep 1: denom(a) ========
    stageT(Qsrc, HID, &QsA[0]);
    stageT(Qsrc + (long)64 * HID, HID, &QsA[4096]);

    float ps_a = 0.0f;
    for (int i = 0; i < 32; ++i) {
        if (i >= 30) asm volatile("s_waitcnt vmcnt(0)" ::: "memory");
        else         asm volatile("s_waitcnt vmcnt(2)" ::: "memory");
        SCHED();
        SBAR(); SCHED();
        if (i < 30) stageT(Qsrc + (long)((i + 2) * 64) * HID, HID, &QsA[((i + 2) % 3) * 4096]);

        f32x4 acc[4];
        #pragma unroll
        for (int x = 0; x < 4; x++)
            #pragma unroll
            for (int r = 0; r < 4; r++) acc[x][r] = 0.0f;

        const ush* Qb = &QsA[(i % 3) * 4096];
        __builtin_amdgcn_s_setprio(1);
        #pragma unroll
        for (int ks = 0; ks < 2; ks++) {
            const int uo = (ks ? (u0 ^ 4) : u0) * 8;
            short8 aq[4];
            #pragma unroll
            for (int mf = 0; mf < 4; mf++)
                aq[mf] = *reinterpret_cast<const short8*>(&Qb[(mf * 16 + l16) * 64 + uo]);
            #pragma unroll
            for (int mf = 0; mf < 4; mf++)
                acc[mf] = __builtin_amdgcn_mfma_f32_16x16x32_bf16(aq[mf], bk_a[ks], acc[mf], 0, 0, 0);
        }
        __builtin_amdgcn_s_setprio(0);

        #pragma unroll
        for (int mf = 0; mf < 4; mf++) {
            float s = 0.0f;
            #pragma unroll
            for (int r = 0; r < 4; r++) s += exp2f(acc[mf][r]);
            ps_a += s;
        }
    }
    float inv_a;
    {
        float v = ps_a;
        v += __shfl_xor(v, 16);
        v += __shfl_xor(v, 32);
        inv_a = 1.0f / v;
    }

    // ======== sweep 2: B(a) + denom(b) ========
    SBAR();
    stageT(Qsrc, HID, &QsA[0]);
    stageT(Vsrc, SEQ, &VtA[0]);
    stageT(Qsrc + (long)64 * HID, HID, &QsA[4096]);
    stageT(Vsrc + 64, SEQ, &VtA[4096]);

    float ps_b = 0.0f;
    f32x4 octx[4];
    #pragma unroll
    for (int y = 0; y < 4; y++)
        #pragma unroll
        for (int r = 0; r < 4; r++) octx[y][r] = 0.0f;

    for (int i = 0; i < 32; ++i) {
        const int q0 = i << 6;
        if (i == 0)       asm volatile("s_waitcnt vmcnt(4)"  ::: "memory");
        else if (i == 1)  asm volatile("s_waitcnt vmcnt(8)"  ::: "memory");
        else if (i == 31) asm volatile("s_waitcnt vmcnt(8)"  ::: "memory");
        else              asm volatile("s_waitcnt vmcnt(12)" ::: "memory");
        SCHED();
        SBAR(); SCHED();
        if (i < 30) {
            stageT(Qsrc + (long)((i + 2) * 64) * HID, HID, &QsA[((i + 2) % 3) * 4096]);
            stageT(Vsrc + (i + 2) * 64, SEQ, &VtA[((i + 2) % 3) * 4096]);
        }

        f32x4 aA[4], aB[4];
        #pragma unroll
        for (int x = 0; x < 4; x++)
            #pragma unroll
            for (int r = 0; r < 4; r++) { aA[x][r] = 0.0f; aB[x][r] = 0.0f; }

        const ush* Qb = &QsA[(i % 3) * 4096];
        __builtin_amdgcn_s_setprio(1);
        #pragma unroll
        for (int ks = 0; ks < 2; ks++) {
            const int uo = (ks ? (u0 ^ 4) : u0) * 8;
            short8 aq[4];
            #pragma unroll
            for (int mf = 0; mf < 4; mf++)
                aq[mf] = *reinterpret_cast<const short8*>(&Qb[(mf * 16 + l16) * 64 + uo]);
            #pragma unroll
            for (int mf = 0; mf < 4; mf++)
                aA[mf] = __builtin_amdgcn_mfma_f32_16x16x32_bf16(aq[mf], bk_a[ks], aA[mf], 0, 0, 0);
            #pragma unroll
            for (int mf = 0; mf < 4; mf++)
                aB[mf] = __builtin_amdgcn_mfma_f32_16x16x32_bf16(aq[mf], bk_b[ks], aB[mf], 0, 0, 0);
        }
        __builtin_amdgcn_s_setprio(0);

        // softmax(a) -> At (wave-private 16 rows)
        {
            const int krl = wv * 16 + l16;
            #pragma unroll
            for (int mf = 0; mf < 4; mf++) {
                const int qc = mf * 16 + lq * 4;
                float p0 = exp2f(aA[mf][0]) * inv_a;
                float p1 = exp2f(aA[mf][1]) * inv_a;
                float p2 = exp2f(aA[mf][2]) * inv_a;
                float p3 = exp2f(aA[mf][3]) * inv_a;
                unsigned int w0, w1;
                asm volatile("v_cvt_pk_bf16_f32 %0, %1, %2" : "=v"(w0) : "v"(p0), "v"(p1));
                asm volatile("v_cvt_pk_bf16_f32 %0, %1, %2" : "=v"(w1) : "v"(p2), "v"(p3));
                *reinterpret_cast<uint2*>(&At[krl][qc]) = make_uint2(w0, w1);
            }
        }
        asm volatile("s_waitcnt lgkmcnt(0)" ::: "memory");
        SCHED();

        uint2 wreg[4];
        #pragma unroll
        for (int j = 0; j < 4; ++j)
            wreg[j] = *reinterpret_cast<const uint2*>(&At[wv * 16 + j * 4 + rlo][qc2]);

        // PV(a) from V slot i%3
        const ush* Vb = &VtA[(i % 3) * 4096];
        __builtin_amdgcn_s_setprio(1);
        #pragma unroll
        for (int ks = 0; ks < 2; ks++) {
            const int uo = (ks ? (u0 ^ 4) : u0) * 8;
            short8 a = *reinterpret_cast<const short8*>(&At[wv * 16 + l16][ks * 32 + lq * 8]);
            #pragma unroll
            for (int nf = 0; nf < 4; nf++) {
                short8 bv = *reinterpret_cast<const short8*>(&Vb[(nf * 16 + l16) * 64 + uo]);
                octx[nf] = __builtin_amdgcn_mfma_f32_16x16x32_bf16(a, bv, octx[nf], 0, 0, 0);
            }
        }
        __builtin_amdgcn_s_setprio(0);

        // denom(b)
        #pragma unroll
        for (int mf = 0; mf < 4; mf++) {
            float s = 0.0f;
            #pragma unroll
            for (int r = 0; r < 4; r++) s += exp2f(aB[mf][r]);
            ps_b += s;
        }

        // attn(a) stores LAST: 4 rows x 256B contiguous per instr, nontemporal
        #pragma unroll
        for (int j = 0; j < 4; ++j) {
            const int rl = rowbase_a + wv * 16 + j * 4 + rlo;
            f32x4 st;
            st[0] = __uint_as_float(wreg[j].x << 16);
            st[1] = __uint_as_float(wreg[j].x & 0xffff0000u);
            st[2] = __uint_as_float(wreg[j].y << 16);
            st[3] = __uint_as_float(wreg[j].y & 0xffff0000u);
            __builtin_nontemporal_store(st,
                reinterpret_cast<f32x4*>(attnp + ((long)bh * SEQ + rl) * SEQ + q0 + qc2));
        }
    }
    float inv_b;
    {
        float v = ps_b;
        v += __shfl_xor(v, 16);
        v += __shfl_xor(v, 32);
        inv_b = 1.0f / v;
    }

    // epilogue(a): out = gate * ctx
    #pragma unroll
    for (int nf = 0; nf < 4; nf++) {
        int col = colbase + nf * 16 + l16;
        #pragma unroll
        for (int r = 0; r < 4; r++) {
            long idx = (long)(tb + rowbase_a + wv * 16 + lq * 4 + r) * HID + col;
            float g = __builtin_nontemporal_load(&outp[idx]);
            __builtin_nontemporal_store(g * octx[nf][r], &outp[idx]);
        }
    }

    // ======== sweep 3: B(b) ========
    SBAR();   // all waves fully out of sweep 2 before slot restaging
    stageT(Qsrc, HID, &QsA[0]);
    stageT(Vsrc, SEQ, &VtA[0]);
    stageT(Qsrc + (long)64 * HID, HID, &QsA[4096]);
    stageT(Vsrc + 64, SEQ, &VtA[4096]);

    #pragma unroll
    for (int y = 0; y < 4; y++)
        #pragma unroll
        for (int r = 0; r < 4; r++) octx[y][r] = 0.0f;

    for (int i = 0; i < 32; ++i) {
        const int q0 = i << 6;
        if (i == 0)       asm volatile("s_waitcnt vmcnt(4)"  ::: "memory");
        else if (i == 1)  asm volatile("s_waitcnt vmcnt(8)"  ::: "memory");
        else if (i == 31) asm volatile("s_waitcnt vmcnt(8)"  ::: "memory");
        else              asm volatile("s_waitcnt vmcnt(12)" ::: "memory");
        SCHED();
        SBAR(); SCHED();
        if (i < 30) {
            stageT(Qsrc + (long)((i + 2) * 64) * HID, HID, &QsA[((i + 2) % 3) * 4096]);
            stageT(Vsrc + (i + 2) * 64, SEQ, &VtA[((i + 2) % 3) * 4096]);
        }

        f32x4 aB[4];
        #pragma unroll
        for (int x = 0; x < 4; x++)
            #pragma unroll
            for (int r = 0; r < 4; r++) aB[x][r] = 0.0f;

        const ush* Qb = &QsA[(i % 3) * 4096];
        __builtin_amdgcn_s_setprio(1);
        #pragma unroll
        for (int ks = 0; ks < 2; ks++) {
            const int uo = (ks ? (u0 ^ 4) : u0) * 8;
            short8 aq[4];
            #pragma unroll
            for (int mf = 0; mf < 4; mf++)
                aq[mf] = *reinterpret_cast<const short8*>(&Qb[(mf * 16 + l16) * 64 + uo]);
            #pragma unroll
            for (int mf = 0; mf < 4; mf++)
                aB[mf] = __builtin_amdgcn_mfma_f32_16x16x32_bf16(aq[mf], bk_b[ks], aB[mf], 0, 0, 0);
        }
        __builtin_amdgcn_s_setprio(0);

        {
            const int krl = wv * 16 + l16;
            #pragma unroll
            for (int mf = 0; mf < 4; mf++) {
                const int qc = mf * 16 + lq * 4;
                float p0 = exp2f(aB[mf][0]) * inv_b;
                float p1 = exp2f(aB[mf][1]) * inv_b;
                float p2 = exp2f(aB[mf][2]) * inv_b;
                float p3 = exp2f(aB[mf][3]) * inv_b;
                unsigned int w0, w1;
                asm volatile("v_cvt_pk_bf16_f32 %0, %1, %2" : "=v"(w0) : "v"(p0), "v"(p1));
                asm volatile("v_cvt_pk_bf16_f32 %0, %1, %2" : "=v"(w1) : "v"(p2), "v"(p3));
                *reinterpret_cast<uint2*>(&At[krl][qc]) = make_uint2(w0, w1);
            }
        }
        asm volatile("s_waitcnt lgkmcnt(0)" ::: "memory");
        SCHED();

        uint2 wreg[4];
        #pragma unroll
        for (int j = 0; j < 4; ++j)
            wreg[j] = *reinterpret_cast<const uint2*>(&At[wv * 16 + j * 4 + rlo][qc2]);

        const ush* Vb = &VtA[(i % 3) * 4096];
        __builtin_amdgcn_s_setprio(1);
        #pragma unroll
        for (int ks = 0; ks < 2; ks++) {
            const int uo = (ks ? (u0 ^ 4) : u0) * 8;
            short8 a = *reinterpret_cast<const short8*>(&At[wv * 16 + l16][ks * 32 + lq * 8]);
            #pragma unroll
            for (int nf = 0; nf < 4; nf++) {
                short8 bv = *reinterpret_cast<const short8*>(&Vb[(nf * 16 + l16) * 64 + uo]);
                octx[nf] = __builtin_amdgcn_mfma_f32_16x16x32_bf16(a, bv, octx[nf], 0, 0, 0);
            }
        }
        __builtin_amdgcn_s_setprio(0);

        #pragma unroll
        for (int j = 0; j < 4; ++j) {
            const int rl = rowbase_b + wv * 16 + j * 4 + rlo;
            f32x4 st;
            st[0] = __uint_as_float(wreg[j].x << 16);
            st[1] = __uint_as_float(wreg[j].x & 0xffff0000u);
            st[2] = __uint_as_float(wreg[j].y << 16);
            st[3] = __uint_as_float(wreg[j].y & 0xffff0000u);
            __builtin_nontemporal_store(st,
                reinterpret_cast<f32x4*>(attnp + ((long)bh * SEQ + rl) * SEQ + q0 + qc2));
        }
    }

    // epilogue(b)
    #pragma unroll
    for (int nf = 0; nf < 4; nf++) {
        int col = colbase + nf * 16 + l16;
        #pragma unroll
        for (int r = 0; r < 4; r++) {
            long idx = (long)(tb + rowbase_b + wv * 16 + lq * 4 + r) * HID + col;
            float g = __builtin_nontemporal_load(&outp[idx]);
            __builtin_nontemporal_store(g * octx[nf][r], &outp[idx]);
        }
    }
}

extern "C" void kernel_launch(void* const* d_in, const int* in_sizes, int n_in,
                              void* d_out, int out_size, void* d_ws, size_t ws_size,
                              hipStream_t stream)
{
    const float* X  = (const float*)d_in[0];
    const float* Wq = (const float*)d_in[1];
    const float* Wk = (const float*)d_in[2];
    const float* Wg = (const float*)d_in[3];
    const float* bg = (const float*)d_in[4];

    float* outp  = (float*)d_out;
    float* attnp = outp + (long)NTOK * HID;

    ush* Qbf = (ush*)d_ws;
    ush* Kbf = Qbf + (long)NTOK * HID;
    ush* VtG = Kbf + (long)NTOK * HID;

    ush* Xbf = (ush*)(outp + 134742016L);
    ush* Wbf = Xbf + (long)NTOK * HID;

    cvt_kernel<<<3584, 256, 0, stream>>>(X, Wq, Wk, Wg, Xbf, Wbf);
    proj_kernel<<<dim3(24, 32), 256, 0, stream>>>(Xbf, Wbf, bg, Qbf, Kbf, VtG, outp);
    attn_kernel<<<512, 256, 0, stream>>>(Qbf, Kbf, VtG, outp, attnp);
}